// Round 5
// baseline (143.234 us; speedup 1.0000x reference)
//
#include <hip/hip_runtime.h>

// Updater: B=4194304 sequential scan, 3 independent scalar recurrences
//   net' = sigmoid(10*(net + u - 0.5)), u = W*x + b, pred = x . net'
// Chunked-scan with certified warm-up (monotone map -> [0,1] bracket, early
// exit to single trajectory, geometric backoff ending at exact net0).
// Structure: 1024 blocks x 2 tiles of 2048 steps. Per tile: x window staged
// in LDS via coalesced float4 (register-prefetched during previous tile's
// compute), preds transposed through LDS for lane-contiguous float4 stores.
// LDS 33KB -> 4 blocks/CU, all 1024 blocks co-resident (no tail).

#if __has_builtin(__builtin_amdgcn_exp2f)
#define EXP2F(v) __builtin_amdgcn_exp2f(v)
#else
#define EXP2F(v) __expf(0.6931471805599453f * (v))
#endif

typedef float vf4 __attribute__((ext_vector_type(4)));  // native clang vector

namespace {
constexpr int   BTOT   = 4194304;
constexpr int   BLOCK  = 256;
constexpr int   TILE   = 2048;                 // steps per tile
constexpr int   CHUNK  = TILE / BLOCK;         // 8 steps / thread / tile
constexpr int   NTILES = 2;
constexpr int   GRID   = BTOT / (TILE * NTILES); // 1024
constexpr int   WARM   = 16;
constexpr int   XF     = (TILE + WARM) * 3;    // 6192 floats = 24.2 KB
constexpr int   XF4    = XF / 4;               // 1548 float4
constexpr float KEXP   = -14.426950408889634f; // -10 * log2(e)
constexpr float EPS    = 1e-6f;
}

// sigmoid(10*(n+u-0.5)) = rcp(1 + exp2(KEXP*n + c)), c = (KEXP*W)x + KEXP*(b-.5)
#define CVALS(X0, X1, X2)                                                      \
  const float c0 = fmaf(kw00, (X0), fmaf(kw01, (X1), fmaf(kw02, (X2), kb0)));  \
  const float c1 = fmaf(kw10, (X0), fmaf(kw11, (X1), fmaf(kw12, (X2), kb1)));  \
  const float c2 = fmaf(kw20, (X0), fmaf(kw21, (X1), fmaf(kw22, (X2), kb2)));

#define SIG(N, C) __builtin_amdgcn_rcpf(1.0f + EXP2F(fmaf(KEXP, (N), (C))))

#define US(X0, X1, X2)                                                         \
  do {                                                                         \
    CVALS(X0, X1, X2)                                                          \
    lo0 = SIG(lo0, c0); hi0 = SIG(hi0, c0);                                    \
    lo1 = SIG(lo1, c1); hi1 = SIG(hi1, c1);                                    \
    lo2 = SIG(lo2, c2); hi2 = SIG(hi2, c2);                                    \
  } while (0)

#define SS(X0, X1, X2)                                                         \
  do {                                                                         \
    CVALS(X0, X1, X2)                                                          \
    m0 = SIG(m0, c0); m1 = SIG(m1, c1); m2 = SIG(m2, c2);                      \
  } while (0)

#define MS(IDX, X0, X1, X2)                                                    \
  do {                                                                         \
    CVALS(X0, X1, X2)                                                          \
    m0 = SIG(m0, c0); m1 = SIG(m1, c1); m2 = SIG(m2, c2);                      \
    pr[(IDX)] = fmaf((X0), m0, fmaf((X1), m1, (X2) * m2));                     \
  } while (0)

#define US4(A, B4, C4)                                                         \
  do { US((A).x,(A).y,(A).z); US((A).w,(B4).x,(B4).y);                         \
       US((B4).z,(B4).w,(C4).x); US((C4).y,(C4).z,(C4).w); } while (0)
#define SS4(A, B4, C4)                                                         \
  do { SS((A).x,(A).y,(A).z); SS((A).w,(B4).x,(B4).y);                         \
       SS((B4).z,(B4).w,(C4).x); SS((C4).y,(C4).z,(C4).w); } while (0)
#define MS4(Q, A, B4, C4)                                                      \
  do { MS(4*(Q)+0,(A).x,(A).y,(A).z); MS(4*(Q)+1,(A).w,(B4).x,(B4).y);         \
       MS(4*(Q)+2,(B4).z,(B4).w,(C4).x); MS(4*(Q)+3,(C4).y,(C4).z,(C4).w); } while (0)

__global__ __launch_bounds__(BLOCK, 4) void Updater_65395172049297_kernel(
    const float* __restrict__ x, const float* __restrict__ W,
    const float* __restrict__ bv, const float* __restrict__ n0v,
    float* __restrict__ out)
{
    __shared__ __align__(16) float xs[XF];   // x window [tileStart-16, tileStart+TILE)
    __shared__ __align__(16) float ps[TILE]; // preds (transpose for coalesced store)

    const float kw00 = KEXP * W[0], kw01 = KEXP * W[1], kw02 = KEXP * W[2];
    const float kw10 = KEXP * W[3], kw11 = KEXP * W[4], kw12 = KEXP * W[5];
    const float kw20 = KEXP * W[6], kw21 = KEXP * W[7], kw22 = KEXP * W[8];
    const float kb0 = KEXP * (bv[0] - 0.5f);
    const float kb1 = KEXP * (bv[1] - 0.5f);
    const float kb2 = KEXP * (bv[2] - 0.5f);
    const float n00 = n0v[0], n01 = n0v[1], n02 = n0v[2];

    const int  t          = threadIdx.x;
    const long blockStart = (long)blockIdx.x * (TILE * NTILES);

    float4 pf[7];

    // ---- stage tile 0 ----
    {
        long wbeg = blockStart - WARM;
        int  ofs4 = 0;
        if (wbeg < 0) { wbeg = 0; ofs4 = (WARM * 3) / 4; }  // block 0: skip prefix
        const float4* src = reinterpret_cast<const float4*>(x + 3 * wbeg);
        const int     n4  = XF4 - ofs4;                     // 1548 or 1536
        float4*       dst = reinterpret_cast<float4*>(xs) + ofs4;
#pragma unroll
        for (int i = 0; i < 6; ++i) pf[i] = src[t + i * BLOCK];
        const bool x7 = (t < n4 - 6 * BLOCK);
        if (x7) pf[6] = src[t + 6 * BLOCK];
#pragma unroll
        for (int i = 0; i < 6; ++i) dst[t + i * BLOCK] = pf[i];
        if (x7) dst[t + 6 * BLOCK] = pf[6];
    }
    __syncthreads();

    for (int tile = 0; tile < NTILES; ++tile) {
        const long tileStart = blockStart + (long)tile * TILE;

        // prefetch next tile into registers (overlaps this tile's compute)
        if (tile + 1 < NTILES) {
            const float4* src =
                reinterpret_cast<const float4*>(x + 3 * (tileStart + TILE - WARM));
#pragma unroll
            for (int i = 0; i < 6; ++i) pf[i] = src[t + i * BLOCK];
            if (t < XF4 - 6 * BLOCK) pf[6] = src[t + 6 * BLOCK];
        }

        // ---- warm-up ----
        const long start = tileStart + (long)t * CHUNK;
        const int  wl    = (start < (long)WARM) ? (int)start : WARM;
        const bool exact = (start == (long)wl);          // reaches t=0
        const int  gw    = wl >> 2;
        const int  lbeg  = (int)(start - wl - tileStart + WARM) * 3; // float idx

        float lo0, lo1, lo2, hi0, hi1, hi2, m0, m1, m2;
        bool  conv = false;
        int   g    = 0;

        if (exact) {
            m0 = n00; m1 = n01; m2 = n02; conv = true;
        } else {
            lo0 = lo1 = lo2 = 0.0f; hi0 = hi1 = hi2 = 1.0f;
            for (; g < gw; ) {
                const float4* p = reinterpret_cast<const float4*>(&xs[lbeg + 12 * g]);
                const float4 a = p[0], b4 = p[1], c4 = p[2];
                US4(a, b4, c4);
                ++g;
                conv = ((hi0 - lo0) < EPS) & ((hi1 - lo1) < EPS) & ((hi2 - lo2) < EPS);
                if (__all(conv)) break;
            }
            if (conv) { m0 = 0.5f*(lo0+hi0); m1 = 0.5f*(lo1+hi1); m2 = 0.5f*(lo2+hi2); }
        }

        if (conv) {
            for (; g < gw; ++g) {
                const float4* p = reinterpret_cast<const float4*>(&xs[lbeg + 12 * g]);
                const float4 a = p[0], b4 = p[1], c4 = p[2];
                SS4(a, b4, c4);
            }
        } else {
            // rare certified backoff: extend warm-up 4x per attempt (global x)
            for (int a2 = 1; a2 < 12 && !conv; ++a2) {
                long wl2 = (long)WARM << (2 * a2);
                long bgn = start - wl2;
                bool ex2 = (bgn <= 0);
                if (ex2) bgn = 0;
                if (ex2) { lo0 = hi0 = n00; lo1 = hi1 = n01; lo2 = hi2 = n02; }
                else     { lo0 = lo1 = lo2 = 0.0f; hi0 = hi1 = hi2 = 1.0f; }
                for (long s2 = bgn; s2 < start; ++s2) {
                    const float X0 = x[3*s2], X1 = x[3*s2+1], X2 = x[3*s2+2];
                    US(X0, X1, X2);
                }
                conv = ex2 || (((hi0 - lo0) < EPS) & ((hi1 - lo1) < EPS) &
                               ((hi2 - lo2) < EPS));
            }
            m0 = 0.5f*(lo0+hi0); m1 = 0.5f*(lo1+hi1); m2 = 0.5f*(lo2+hi2);
        }

        // ---- main: CHUNK=8 steps from LDS ----
        const int lm = (int)(start - tileStart + WARM) * 3;  // 24t + 48
        float pr[CHUNK];
        {
            const float4* p = reinterpret_cast<const float4*>(&xs[lm]);
            const float4 a0 = p[0], b0_ = p[1], c0_ = p[2];
            const float4 a1 = p[3], b1_ = p[4], c1_ = p[5];
            MS4(0, a0, b0_, c0_);
            MS4(1, a1, b1_, c1_);
        }

        // preds -> LDS (transpose for coalesced store)
        {
            float4* pp = reinterpret_cast<float4*>(&ps[t * CHUNK]);
            pp[0] = make_float4(pr[0], pr[1], pr[2], pr[3]);
            pp[1] = make_float4(pr[4], pr[5], pr[6], pr[7]);
        }
        __syncthreads();

        // coalesced nontemporal store of this tile's preds
        {
            vf4*       o4  = reinterpret_cast<vf4*>(out + tileStart);
            const vf4* ps4 = reinterpret_cast<const vf4*>(ps);
            __builtin_nontemporal_store(ps4[t], &o4[t]);
            __builtin_nontemporal_store(ps4[t + BLOCK], &o4[t + BLOCK]);
        }

        // dump prefetched next tile regs -> LDS
        if (tile + 1 < NTILES) {
            __syncthreads();   // all reads of xs done before overwrite
            float4* dst = reinterpret_cast<float4*>(xs);
#pragma unroll
            for (int i = 0; i < 6; ++i) dst[t + i * BLOCK] = pf[i];
            if (t < XF4 - 6 * BLOCK) dst[t + 6 * BLOCK] = pf[6];
            __syncthreads();
        }
    }
}

extern "C" void kernel_launch(void* const* d_in, const int* in_sizes, int n_in,
                              void* d_out, int out_size, void* d_ws, size_t ws_size,
                              hipStream_t stream) {
    const float* x   = (const float*)d_in[0];   // (B,1,3)
    const float* W   = (const float*)d_in[1];   // (3,3)
    const float* bv  = (const float*)d_in[2];   // (3,)
    const float* n0v = (const float*)d_in[3];   // (3,1)
    float*       out = (float*)d_out;           // (B,1)
    Updater_65395172049297_kernel<<<GRID, BLOCK, 0, stream>>>(x, W, bv, n0v, out);
}

// Round 6
// 114.175 us; speedup vs baseline: 1.2545x; 1.2545x over previous
//
#include <hip/hip_runtime.h>

// Updater: B=4194304 sequential scan, 3 independent scalar recurrences
//   net' = sigmoid(10*(net + u - 0.5)), u = W*x + b, pred = x . net'
// Chunked-scan with certified warm-up (monotone map -> [0,1] bracket, early
// exit to single trajectory, geometric backoff ending at exact net0).
// 1024 blocks x 4096-step tile. x window (49.3 KB) staged in LDS once via
// coalesced float4; preds transposed through a +1-padded LDS layout (aliased
// over the dead x window) for fully-coalesced REGULAR stores (no nt flag --
// R5 showed nontemporal 16B stores bypass L2 combining: 4x WRITE_SIZE).

#if __has_builtin(__builtin_amdgcn_exp2f)
#define EXP2F(v) __builtin_amdgcn_exp2f(v)
#else
#define EXP2F(v) __expf(0.6931471805599453f * (v))
#endif

namespace {
constexpr int   BTOT  = 4194304;
constexpr int   BLOCK = 256;
constexpr int   CHUNK = 16;                  // steps per thread
constexpr int   TILE  = BLOCK * CHUNK;       // 4096 steps per block
constexpr int   GRID  = BTOT / TILE;         // 1024
constexpr int   WARM  = 16;
constexpr int   XF    = (TILE + WARM) * 3;   // 12336 floats = 49.3 KB
constexpr int   XF4   = XF / 4;              // 3084 float4
constexpr int   PROW  = CHUNK + 1;           // padded pred row (17, odd stride)
constexpr float KEXP  = -14.426950408889634f; // -10 * log2(e)
constexpr float EPS   = 1e-6f;
}

// sigmoid(10*(n+u-0.5)) = rcp(1 + exp2(KEXP*n + c)), c = (KEXP*W)x + KEXP*(b-.5)
#define CVALS(X0, X1, X2)                                                      \
  const float c0 = fmaf(kw00, (X0), fmaf(kw01, (X1), fmaf(kw02, (X2), kb0)));  \
  const float c1 = fmaf(kw10, (X0), fmaf(kw11, (X1), fmaf(kw12, (X2), kb1)));  \
  const float c2 = fmaf(kw20, (X0), fmaf(kw21, (X1), fmaf(kw22, (X2), kb2)));

#define SIG(N, C) __builtin_amdgcn_rcpf(1.0f + EXP2F(fmaf(KEXP, (N), (C))))

#define US(X0, X1, X2)                                                         \
  do {                                                                         \
    CVALS(X0, X1, X2)                                                          \
    lo0 = SIG(lo0, c0); hi0 = SIG(hi0, c0);                                    \
    lo1 = SIG(lo1, c1); hi1 = SIG(hi1, c1);                                    \
    lo2 = SIG(lo2, c2); hi2 = SIG(hi2, c2);                                    \
  } while (0)

#define SS(X0, X1, X2)                                                         \
  do {                                                                         \
    CVALS(X0, X1, X2)                                                          \
    m0 = SIG(m0, c0); m1 = SIG(m1, c1); m2 = SIG(m2, c2);                      \
  } while (0)

#define MS(IDX, X0, X1, X2)                                                    \
  do {                                                                         \
    CVALS(X0, X1, X2)                                                          \
    m0 = SIG(m0, c0); m1 = SIG(m1, c1); m2 = SIG(m2, c2);                      \
    pr[(IDX)] = fmaf((X0), m0, fmaf((X1), m1, (X2) * m2));                     \
  } while (0)

#define US4(A, B4, C4)                                                         \
  do { US((A).x,(A).y,(A).z); US((A).w,(B4).x,(B4).y);                         \
       US((B4).z,(B4).w,(C4).x); US((C4).y,(C4).z,(C4).w); } while (0)
#define SS4(A, B4, C4)                                                         \
  do { SS((A).x,(A).y,(A).z); SS((A).w,(B4).x,(B4).y);                         \
       SS((B4).z,(B4).w,(C4).x); SS((C4).y,(C4).z,(C4).w); } while (0)
#define MS4(Q, A, B4, C4)                                                      \
  do { MS(4*(Q)+0,(A).x,(A).y,(A).z); MS(4*(Q)+1,(A).w,(B4).x,(B4).y);         \
       MS(4*(Q)+2,(B4).z,(B4).w,(C4).x); MS(4*(Q)+3,(C4).y,(C4).z,(C4).w); } while (0)

__global__ __launch_bounds__(BLOCK, 4) void Updater_65395172049297_kernel(
    const float* __restrict__ x, const float* __restrict__ W,
    const float* __restrict__ bv, const float* __restrict__ n0v,
    float* __restrict__ out)
{
    __shared__ __align__(16) float xs[XF];  // x window; later aliased as preds

    const float kw00 = KEXP * W[0], kw01 = KEXP * W[1], kw02 = KEXP * W[2];
    const float kw10 = KEXP * W[3], kw11 = KEXP * W[4], kw12 = KEXP * W[5];
    const float kw20 = KEXP * W[6], kw21 = KEXP * W[7], kw22 = KEXP * W[8];
    const float kb0 = KEXP * (bv[0] - 0.5f);
    const float kb1 = KEXP * (bv[1] - 0.5f);
    const float kb2 = KEXP * (bv[2] - 0.5f);
    const float n00 = n0v[0], n01 = n0v[1], n02 = n0v[2];

    const int  t = threadIdx.x;
    const long S = (long)blockIdx.x * TILE;

    // ---- stage x window [S-WARM, S+TILE) into LDS (coalesced float4) ----
    if (blockIdx.x == 0) {
        // no prefix before t=0; xs[0..48) left unstaged (never read: thread 0 exact)
        const float4* src = reinterpret_cast<const float4*>(x);
        float4*       dst = reinterpret_cast<float4*>(xs) + (WARM * 3) / 4;
#pragma unroll
        for (int i = 0; i < 12; ++i) dst[t + i * BLOCK] = src[t + i * BLOCK];
    } else {
        const float4* src = reinterpret_cast<const float4*>(x + 3 * (S - WARM));
        float4*       dst = reinterpret_cast<float4*>(xs);
#pragma unroll
        for (int i = 0; i < 12; ++i) dst[t + i * BLOCK] = src[t + i * BLOCK];
        if (t < XF4 - 12 * BLOCK) dst[12 * BLOCK + t] = src[12 * BLOCK + t];
    }
    __syncthreads();

    // ---- warm-up ----
    const long start = S + (long)t * CHUNK;
    const int  wl    = (start < (long)WARM) ? (int)start : WARM;  // 0 or 16
    const bool exact = (start == (long)wl);                       // thread 0 of block 0
    const int  gw    = wl >> 2;
    const int  lbeg  = 48 * t;   // xs float idx of warm-window begin

    float lo0, lo1, lo2, hi0, hi1, hi2, m0, m1, m2;
    bool  conv = false;
    int   g    = 0;

    if (exact) {
        m0 = n00; m1 = n01; m2 = n02; conv = true;
    } else {
        lo0 = lo1 = lo2 = 0.0f; hi0 = hi1 = hi2 = 1.0f;
        for (; g < gw; ) {
            const float4* p = reinterpret_cast<const float4*>(&xs[lbeg + 12 * g]);
            const float4 a = p[0], b4 = p[1], c4 = p[2];
            US4(a, b4, c4);
            ++g;
            conv = ((hi0 - lo0) < EPS) & ((hi1 - lo1) < EPS) & ((hi2 - lo2) < EPS);
            if (__all(conv)) break;
        }
        if (conv) { m0 = 0.5f*(lo0+hi0); m1 = 0.5f*(lo1+hi1); m2 = 0.5f*(lo2+hi2); }
    }

    if (conv) {
        // single-trajectory remainder of warm-up (still advances state to `start`)
        for (; g < gw; ++g) {
            const float4* p = reinterpret_cast<const float4*>(&xs[lbeg + 12 * g]);
            const float4 a = p[0], b4 = p[1], c4 = p[2];
            SS4(a, b4, c4);
        }
    } else {
        // rare certified backoff: extend warm-up 4x per attempt (global x reads)
        for (int a2 = 1; a2 < 12 && !conv; ++a2) {
            long wl2 = (long)WARM << (2 * a2);
            long bgn = start - wl2;
            bool ex2 = (bgn <= 0);
            if (ex2) bgn = 0;
            if (ex2) { lo0 = hi0 = n00; lo1 = hi1 = n01; lo2 = hi2 = n02; }
            else     { lo0 = lo1 = lo2 = 0.0f; hi0 = hi1 = hi2 = 1.0f; }
            for (long s2 = bgn; s2 < start; ++s2) {
                const float X0 = x[3*s2], X1 = x[3*s2+1], X2 = x[3*s2+2];
                US(X0, X1, X2);
            }
            conv = ex2 || (((hi0 - lo0) < EPS) & ((hi1 - lo1) < EPS) &
                           ((hi2 - lo2) < EPS));
        }
        m0 = 0.5f*(lo0+hi0); m1 = 0.5f*(lo1+hi1); m2 = 0.5f*(lo2+hi2);
    }

    // ---- main: 16 steps from LDS ----
    const int lm = 48 * t + 48;
    float pr[CHUNK];
#pragma unroll
    for (int q = 0; q < CHUNK / 4; ++q) {
        const float4* p = reinterpret_cast<const float4*>(&xs[lm + 12 * q]);
        const float4 a = p[0], b4 = p[1], c4 = p[2];
        MS4(q, a, b4, c4);
    }

    // ---- preds -> padded LDS transpose (aliases dead x window) ----
    __syncthreads();                       // all xs reads complete
    float* ps = xs;                        // [BLOCK][PROW], 4352 floats
#pragma unroll
    for (int k = 0; k < CHUNK; ++k) ps[t * PROW + k] = pr[k];  // stride 17: conflict-free
    __syncthreads();

    // ---- coalesced regular stores: lane r -> out[S + 256*i + r] ----
#pragma unroll
    for (int i = 0; i < CHUNK; ++i) {
        const int j = 256 * i + t;
        out[S + j] = ps[(j >> 4) * PROW + (j & 15)];
    }
}

extern "C" void kernel_launch(void* const* d_in, const int* in_sizes, int n_in,
                              void* d_out, int out_size, void* d_ws, size_t ws_size,
                              hipStream_t stream) {
    const float* x   = (const float*)d_in[0];   // (B,1,3)
    const float* W   = (const float*)d_in[1];   // (3,3)
    const float* bv  = (const float*)d_in[2];   // (3,)
    const float* n0v = (const float*)d_in[3];   // (3,1)
    float*       out = (float*)d_out;           // (B,1)
    Updater_65395172049297_kernel<<<GRID, BLOCK, 0, stream>>>(x, W, bv, n0v, out);
}